// Round 7
// baseline (246.927 us; speedup 1.0000x reference)
//
#include <hip/hip_runtime.h>
#include <hip/hip_bf16.h>

#define B_SZ 8
#define N_Q 512
#define M_KV 4096
#define DIM 1024
#define INNER 512
#define NHEADS 8
#define HDIM 64

typedef __attribute__((ext_vector_type(4))) float floatx4;
typedef __attribute__((ext_vector_type(8))) short shortx8;
typedef __attribute__((ext_vector_type(4))) short shortx4;

__device__ inline unsigned short f2bf(float f) {
  union { float f; unsigned u; } x; x.f = f;
  unsigned r = x.u + 0x7FFFu + ((x.u >> 16) & 1u);
  return (unsigned short)(r >> 16);
}

__device__ inline shortx8 cvt8(floatx4 a, floatx4 b) {
  shortx8 h;
  h[0] = (short)f2bf(a[0]); h[1] = (short)f2bf(a[1]);
  h[2] = (short)f2bf(a[2]); h[3] = (short)f2bf(a[3]);
  h[4] = (short)f2bf(b[0]); h[5] = (short)f2bf(b[1]);
  h[6] = (short)f2bf(b[2]); h[7] = (short)f2bf(b[3]);
  return h;
}

__device__ inline void gload16(const void* g, void* l) {
  __builtin_amdgcn_global_load_lds(
      (const __attribute__((address_space(1))) void*)g,
      (__attribute__((address_space(3))) void*)l, 16, 0, 0);
}

// W[K][N] fp32 -> Wt[N][K] bf16, LDS-tiled (coalesced both sides).
__global__ void k_transpose_bf16(const float* __restrict__ W,
                                 unsigned short* __restrict__ Wt,
                                 int K, int N) {
  __shared__ unsigned short t[32][36];
  const int kt = blockIdx.x * 32, nt = blockIdx.y * 32;
  const int tr = threadIdx.x >> 3;        // 0..31
  const int tc = (threadIdx.x & 7) * 4;   // 0,4,...,28
  floatx4 v = *reinterpret_cast<const floatx4*>(&W[(long)(kt + tr) * N + nt + tc]);
  #pragma unroll
  for (int j = 0; j < 4; ++j) t[tr][tc + j] = f2bf(v[j]);
  __syncthreads();
  shortx4 o;
  #pragma unroll
  for (int j = 0; j < 4; ++j) o[j] = (short)t[tc + j][tr];
  *reinterpret_cast<shortx4*>(&Wt[(long)(nt + tr) * K + kt + tc]) = o;
}

// Fused K+V projection GEMM on the m97 geometry: 128x128 tile, BK=32,
// 4 waves (2x2, wave tile 64x64), 32KB dbuf LDS (~3 blocks/CU).
// A (ctx fp32) reg-staged first -> cvt waits vmcnt leaves B in flight;
// B (Wkvt bf16 [1024][1024]) via per-wave global_load_lds, swizzle applied
// on the per-lane global source address (slot = chunk ^ ((row>>1)&3)).
__global__ __launch_bounds__(256, 3)
void k_gemm_kv(const float* __restrict__ Actx,
               const unsigned short* __restrict__ Wkvt,
               unsigned short* __restrict__ Kh,
               unsigned short* __restrict__ Vt) {
  __shared__ unsigned short As[2][128 * 32];
  __shared__ unsigned short Bs[2][128 * 32];
  const int tid = threadIdx.x;
  const int lane = tid & 63;
  const int w = tid >> 6;
  const int wr = w >> 1, wc = w & 1;
  const int fr = lane & 15, fc = lane >> 4;

  // XCD-chunked bijective swizzle; nt fastest within XCD (A-panel L2 reuse)
  const int L = ((blockIdx.x & 7) << 8) + (blockIdx.x >> 3);
  const int mt = L >> 3, nt = L & 7;
  const long arow0 = (long)mt << 7;
  const long bcol0 = (long)nt << 7;

  // A staging: thread -> row tid>>1, k-half (16 fp32) tid&1
  const int arow = tid >> 1;
  const int ahalf = tid & 1;
  const int aswz = (arow >> 1) & 3;
  const int as0 = ((2 * ahalf) ^ aswz) * 8;
  const int as1 = ((2 * ahalf + 1) ^ aswz) * 8;
  // B staging: wave w covers 16-row blocks w*2+j; lane -> row +(l>>2), pos l&3
  const int brl = lane >> 2;
  const int bpos = lane & 3;

  floatx4 acc[4][4] = {};

  // prologue: tile 0 -> buf 0 (A reg loads first, then B gloads)
  {
    const float* s = Actx + (arow0 + arow) * 1024 + ahalf * 16;
    floatx4 a0 = *reinterpret_cast<const floatx4*>(s);
    floatx4 a1 = *reinterpret_cast<const floatx4*>(s + 4);
    floatx4 a2 = *reinterpret_cast<const floatx4*>(s + 8);
    floatx4 a3 = *reinterpret_cast<const floatx4*>(s + 12);
    #pragma unroll
    for (int j = 0; j < 2; ++j) {
      int row = (w * 2 + j) * 16 + brl;
      int c = bpos ^ ((row >> 1) & 3);
      gload16(Wkvt + (bcol0 + row) * 1024 + c * 8, &Bs[0][(w * 2 + j) * 512]);
    }
    *reinterpret_cast<shortx8*>(&As[0][arow * 32 + as0]) = cvt8(a0, a1);
    *reinterpret_cast<shortx8*>(&As[0][arow * 32 + as1]) = cvt8(a2, a3);
  }
  __syncthreads();

  for (int i = 0; i < 32; ++i) {
    const int cur = i & 1;
    const bool more = i < 31;
    floatx4 a0, a1, a2, a3;
    if (more) {
      // A regs FIRST...
      const float* s = Actx + (arow0 + arow) * 1024 + (i + 1) * 32 + ahalf * 16;
      a0 = *reinterpret_cast<const floatx4*>(s);
      a1 = *reinterpret_cast<const floatx4*>(s + 4);
      a2 = *reinterpret_cast<const floatx4*>(s + 8);
      a3 = *reinterpret_cast<const floatx4*>(s + 12);
      // ...then B gloads (stay in flight past the cvt's vmcnt wait)
      #pragma unroll
      for (int j = 0; j < 2; ++j) {
        int row = (w * 2 + j) * 16 + brl;
        int c = bpos ^ ((row >> 1) & 3);
        gload16(Wkvt + (bcol0 + row) * 1024 + (i + 1) * 32 + c * 8,
                &Bs[cur ^ 1][(w * 2 + j) * 512]);
      }
    }

    shortx8 af[4], bf[4];
    #pragma unroll
    for (int rb = 0; rb < 4; ++rb) {
      int row = wr * 64 + rb * 16 + fr;
      af[rb] = *reinterpret_cast<const shortx8*>(
          &As[cur][row * 32 + ((fc ^ ((row >> 1) & 3)) * 8)]);
    }
    #pragma unroll
    for (int cb = 0; cb < 4; ++cb) {
      int row = wc * 64 + cb * 16 + fr;
      bf[cb] = *reinterpret_cast<const shortx8*>(
          &Bs[cur][row * 32 + ((fc ^ ((row >> 1) & 3)) * 8)]);
    }
    __builtin_amdgcn_s_setprio(1);
    #pragma unroll
    for (int rb = 0; rb < 4; ++rb) {
      #pragma unroll
      for (int cb = 0; cb < 4; ++cb)
        acc[rb][cb] = __builtin_amdgcn_mfma_f32_16x16x32_bf16(
            af[rb], bf[cb], acc[rb][cb], 0, 0, 0);
    }
    __builtin_amdgcn_s_setprio(0);

    if (more) {
      *reinterpret_cast<shortx8*>(&As[cur ^ 1][arow * 32 + as0]) = cvt8(a0, a1);
      *reinterpret_cast<shortx8*>(&As[cur ^ 1][arow * 32 + as1]) = cvt8(a2, a3);
    }
    __syncthreads();  // vmcnt(0)+lgkmcnt(0)+barrier: next tile ready
  }

  // epilogue: split K / V^T store (branch uniform per block: nt<4 -> K)
  #pragma unroll
  for (int rb = 0; rb < 4; ++rb) {
    #pragma unroll
    for (int cb = 0; cb < 4; ++cb) {
      long gr0 = arow0 + wr * 64 + rb * 16 + fc * 4;
      long gc = bcol0 + wc * 64 + cb * 16 + fr;
      long b = gr0 >> 12, m = gr0 & 4095;
      if (gc < 512) {
        long h = gc >> 6, d = gc & 63;
        #pragma unroll
        for (int r = 0; r < 4; ++r)
          Kh[((((b * 8 + h) << 12) + m + r) << 6) + d] = f2bf(acc[rb][cb][r]);
      } else {
        long h = (gc - 512) >> 6, d = (gc - 512) & 63;
        shortx4 hv;
        #pragma unroll
        for (int r = 0; r < 4; ++r) hv[r] = (short)f2bf(acc[rb][cb][r]);
        *reinterpret_cast<shortx4*>(&Vt[(((b * 8 + h) * 64 + d) << 12) + m]) = hv;
      }
    }
  }
}

// General GEMM (Q-projection, out-projection). 128x256 tile, 8 waves, BK=32,
// dbuf LDS, 2-way-free swizzle (chunk ^ (row>>1)&3 at 64B rows).
template<int MODE, bool ABF, int NCOL, int MBITS>
__global__ __launch_bounds__(512, 4)
void k_gemm(const void* __restrict__ Ap, const unsigned short* __restrict__ Bt,
            void* __restrict__ Cout, const float* __restrict__ bias,
            int M, int N, int K, float oscale) {
  __shared__ unsigned short As[2][128 * 32];
  __shared__ unsigned short Bs[2][256 * 32];
  const int tid = threadIdx.x;
  const int lane = tid & 63;
  const int w = tid >> 6;
  const int wr = w >> 2, wc = w & 3;

  const int cpx = gridDim.x >> 3;
  const int L = (blockIdx.x & 7) * cpx + (blockIdx.x >> 3);
  const long arow0 = (long)(L / NCOL) * 128;
  const long bcol0 = (long)(L % NCOL) * 256;

  const float* Af = (const float*)Ap;
  const unsigned short* Ah = (const unsigned short*)Ap;

  const int lsub = lane >> 2;
  const int lchunk = (lane & 3) ^ ((lane >> 3) & 3);
  const long brow0 = bcol0 + (w * 2 + 0) * 16 + lsub;
  const long brow1 = bcol0 + (w * 2 + 1) * 16 + lsub;
  const long ahrow = arow0 + w * 16 + lsub;
  const int arow = tid >> 2;
  const int acseg = tid & 3;
  const int aswz = arow * 32 + ((acseg ^ ((arow >> 1) & 3)) * 8);

  floatx4 acc[4][4] = {};

  #define STAGE_B(buf, kt)                                                   \
    {                                                                        \
      gload16(Bt + brow0 * K + (kt) + lchunk * 8, &Bs[buf][(w * 2) * 512]);  \
      gload16(Bt + brow1 * K + (kt) + lchunk * 8,                            \
              &Bs[buf][(w * 2 + 1) * 512]);                                  \
    }
  #define STAGE_AH(buf, kt) \
    gload16(Ah + ahrow * K + (kt) + lchunk * 8, &As[buf][w * 512]);

  if (ABF) {
    STAGE_AH(0, 0);
  } else {
    const float* src = Af + (arow0 + arow) * (long)K + acseg * 8;
    floatx4 a0 = *reinterpret_cast<const floatx4*>(src);
    floatx4 a1 = *reinterpret_cast<const floatx4*>(src + 4);
    *reinterpret_cast<shortx8*>(&As[0][aswz]) = cvt8(a0, a1);
  }
  STAGE_B(0, 0);
  __syncthreads();

  const int NK = K >> 5;
  for (int i = 0; i < NK; ++i) {
    const int cur = i & 1;
    const bool more = (i + 1) < NK;
    floatx4 a0, a1;
    if (more) {
      const long ktn = (long)(i + 1) << 5;
      if (ABF) {
        STAGE_AH(cur ^ 1, ktn);
      } else {
        const float* src = Af + (arow0 + arow) * (long)K + ktn + acseg * 8;
        a0 = *reinterpret_cast<const floatx4*>(src);
        a1 = *reinterpret_cast<const floatx4*>(src + 4);
      }
      STAGE_B(cur ^ 1, ktn);
    }

    shortx8 af[4], bf[4];
    #pragma unroll
    for (int rb = 0; rb < 4; ++rb) {
      int row = wr * 64 + rb * 16 + (lane & 15);
      af[rb] = *reinterpret_cast<const shortx8*>(
          &As[cur][row * 32 + (((lane >> 4) ^ ((row >> 1) & 3)) * 8)]);
    }
    #pragma unroll
    for (int cb = 0; cb < 4; ++cb) {
      int row = wc * 64 + cb * 16 + (lane & 15);
      bf[cb] = *reinterpret_cast<const shortx8*>(
          &Bs[cur][row * 32 + (((lane >> 4) ^ ((row >> 1) & 3)) * 8)]);
    }
    #pragma unroll
    for (int rb = 0; rb < 4; ++rb) {
      #pragma unroll
      for (int cb = 0; cb < 4; ++cb)
        acc[rb][cb] = __builtin_amdgcn_mfma_f32_16x16x32_bf16(
            af[rb], bf[cb], acc[rb][cb], 0, 0, 0);
    }

    if (more && !ABF)
      *reinterpret_cast<shortx8*>(&As[cur ^ 1][aswz]) = cvt8(a0, a1);
    __syncthreads();
  }
  #undef STAGE_B
  #undef STAGE_AH

  #pragma unroll
  for (int rb = 0; rb < 4; ++rb) {
    #pragma unroll
    for (int cb = 0; cb < 4; ++cb) {
      long gr0 = arow0 + wr * 64 + rb * 16 + (lane >> 4) * 4;
      long gc  = bcol0 + wc * 64 + cb * 16 + (lane & 15);
      if (MODE == 0) {
        float bv = bias[gc];
        #pragma unroll
        for (int r = 0; r < 4; ++r)
          ((float*)Cout)[(gr0 + r) * N + gc] = acc[rb][cb][r] + bv;
      } else if (MODE == 2) {
        long b = gr0 >> MBITS, m = gr0 & ((1 << MBITS) - 1);
        long h = gc >> 6, d = gc & 63;
        #pragma unroll
        for (int r = 0; r < 4; ++r)
          ((unsigned short*)Cout)[((((b * 8 + h) << MBITS) + m + r) << 6) + d] =
              f2bf(acc[rb][cb][r] * oscale);
      }
    }
  }
}

// Flash attention (unchanged from R3 win).
__global__ __launch_bounds__(256, 2)
void k_attn(const unsigned short* __restrict__ Qh,
            const unsigned short* __restrict__ Kh,
            const unsigned short* __restrict__ Vt,
            unsigned short* __restrict__ Aout) {
  __shared__ unsigned short Ks[64][72];
  __shared__ unsigned short Vs[64][72];
  __shared__ unsigned short QPs[64][72];
  const int tid = threadIdx.x;
  const int lane = tid & 63;
  const int w = tid >> 6;
  const int wg = blockIdx.x;
  const int bh = wg & 63;
  const int qt = wg >> 6;
  const int b = bh >> 3, h = bh & 7;

  const unsigned short* Qbase = Qh + (((long)bh << 9) + qt * 64) * 64;
  const unsigned short* Kbase = Kh + (((long)bh) << 18);
  const unsigned short* Vbase = Vt + (((long)bh) << 18);

  const int sr = tid >> 2;
  const int sc = (tid & 3) * 16;

  {
    const unsigned short* src = Qbase + sr * 64 + sc;
    *reinterpret_cast<shortx8*>(&QPs[sr][sc]) =
        *reinterpret_cast<const shortx8*>(src);
    *reinterpret_cast<shortx8*>(&QPs[sr][sc + 8]) =
        *reinterpret_cast<const shortx8*>(src + 8);
  }
  {
    const unsigned short* ksrc = Kbase + sr * 64 + sc;
    *reinterpret_cast<shortx8*>(&Ks[sr][sc]) =
        *reinterpret_cast<const shortx8*>(ksrc);
    *reinterpret_cast<shortx8*>(&Ks[sr][sc + 8]) =
        *reinterpret_cast<const shortx8*>(ksrc + 8);
    const unsigned short* vsrc = Vbase + ((long)sr << 12) + sc;
    *reinterpret_cast<shortx8*>(&Vs[sr][sc]) =
        *reinterpret_cast<const shortx8*>(vsrc);
    *reinterpret_cast<shortx8*>(&Vs[sr][sc + 8]) =
        *reinterpret_cast<const shortx8*>(vsrc + 8);
  }
  __syncthreads();

  shortx8 qf[2];
  qf[0] = *reinterpret_cast<const shortx8*>(
      &QPs[w * 16 + (lane & 15)][(lane >> 4) * 8]);
  qf[1] = *reinterpret_cast<const shortx8*>(
      &QPs[w * 16 + (lane & 15)][32 + (lane >> 4) * 8]);

  floatx4 o_acc[4] = {};
  float l_part[4] = {0.f, 0.f, 0.f, 0.f};
  shortx8 kpre[2], vpre[2];

  for (int mt = 0; mt < M_KV / 64; ++mt) {
    if (mt < M_KV / 64 - 1) {
      const unsigned short* ksrc = Kbase + ((mt + 1) * 64 + sr) * 64 + sc;
      kpre[0] = *reinterpret_cast<const shortx8*>(ksrc);
      kpre[1] = *reinterpret_cast<const shortx8*>(ksrc + 8);
      const unsigned short* vsrc = Vbase + ((long)sr << 12) + (mt + 1) * 64 + sc;
      vpre[0] = *reinterpret_cast<const shortx8*>(vsrc);
      vpre[1] = *reinterpret_cast<const shortx8*>(vsrc + 8);
    }

    floatx4 s[4];
    #pragma unroll
    for (int cb = 0; cb < 4; ++cb) {
      shortx8 k0 = *reinterpret_cast<const shortx8*>(
          &Ks[cb * 16 + (lane & 15)][(lane >> 4) * 8]);
      shortx8 k1 = *reinterpret_cast<const shortx8*>(
          &Ks[cb * 16 + (lane & 15)][32 + (lane >> 4) * 8]);
      floatx4 z = {};
      z = __builtin_amdgcn_mfma_f32_16x16x32_bf16(qf[0], k0, z, 0, 0, 0);
      s[cb] = __builtin_amdgcn_mfma_f32_16x16x32_bf16(qf[1], k1, z, 0, 0, 0);
    }

    #pragma unroll
    for (int cb = 0; cb < 4; ++cb) {
      #pragma unroll
      for (int r = 0; r < 4; ++r) {
        float pv = __expf(s[cb][r]);
        l_part[r] += pv;
        QPs[w * 16 + (lane >> 4) * 4 + r][cb * 16 + (lane & 15)] = f2bf(pv);
      }
    }

    #pragma unroll
    for (int kk = 0; kk < 2; ++kk) {
      shortx8 pf = *reinterpret_cast<const shortx8*>(
          &QPs[w * 16 + (lane & 15)][kk * 32 + (lane >> 4) * 8]);
      #pragma unroll
      for (int db = 0; db < 4; ++db) {
        shortx8 vf = *reinterpret_cast<const shortx8*>(
            &Vs[db * 16 + (lane & 15)][kk * 32 + (lane >> 4) * 8]);
        o_acc[db] = __builtin_amdgcn_mfma_f32_16x16x32_bf16(
            pf, vf, o_acc[db], 0, 0, 0);
      }
    }

    __syncthreads();
    if (mt < M_KV / 64 - 1) {
      *reinterpret_cast<shortx8*>(&Ks[sr][sc]) = kpre[0];
      *reinterpret_cast<shortx8*>(&Ks[sr][sc + 8]) = kpre[1];
      *reinterpret_cast<shortx8*>(&Vs[sr][sc]) = vpre[0];
      *reinterpret_cast<shortx8*>(&Vs[sr][sc + 8]) = vpre[1];
      __syncthreads();
    }
  }

  float inv[4];
  #pragma unroll
  for (int r = 0; r < 4; ++r) {
    float l = l_part[r];
    l += __shfl_xor(l, 1);
    l += __shfl_xor(l, 2);
    l += __shfl_xor(l, 4);
    l += __shfl_xor(l, 8);
    inv[r] = 1.f / l;
  }
  #pragma unroll
  for (int db = 0; db < 4; ++db) {
    #pragma unroll
    for (int r = 0; r < 4; ++r) {
      int n = qt * 64 + w * 16 + (lane >> 4) * 4 + r;
      long idx = ((long)(b * N_Q + n)) * INNER + h * HDIM + db * 16 + (lane & 15);
      Aout[idx] = f2bf(o_acc[db][r] * inv[r]);
    }
  }
}

extern "C" void kernel_launch(void* const* d_in, const int* in_sizes, int n_in,
                              void* d_out, int out_size, void* d_ws, size_t ws_size,
                              hipStream_t stream) {
  const float* x   = (const float*)d_in[0];
  const float* ctx = (const float*)d_in[1];
  const float* Wq  = (const float*)d_in[2];
  const float* Wk  = (const float*)d_in[3];
  const float* Wv  = (const float*)d_in[4];
  const float* Wo  = (const float*)d_in[5];
  const float* bo  = (const float*)d_in[6];
  float* out = (float*)d_out;

  char* ws = (char*)d_ws;
  unsigned short* Qh   = (unsigned short*)(ws);                    // 4MB
  unsigned short* Kh   = (unsigned short*)(ws + (4ull  << 20));    // 32MB
  unsigned short* Vt   = (unsigned short*)(ws + (36ull << 20));    // 32MB
  unsigned short* Aat  = (unsigned short*)(ws + (68ull << 20));    // 4MB (bf16)
  unsigned short* Wqt  = (unsigned short*)(ws + (72ull << 20));    // 1MB
  unsigned short* Wkvt = (unsigned short*)(ws + (73ull << 20));    // 2MB
  unsigned short* Wot  = (unsigned short*)(ws + (75ull << 20));    // 1MB

  // weight transposes (LDS-tiled, coalesced)
  k_transpose_bf16<<<dim3(DIM / 32, INNER / 32), dim3(256), 0, stream>>>(
      Wq, Wqt, DIM, INNER);
  k_transpose_bf16<<<dim3(DIM / 32, INNER / 32), dim3(256), 0, stream>>>(
      Wk, Wkvt, DIM, INNER);
  k_transpose_bf16<<<dim3(DIM / 32, INNER / 32), dim3(256), 0, stream>>>(
      Wv, Wkvt + (size_t)INNER * DIM, DIM, INNER);
  k_transpose_bf16<<<dim3(INNER / 32, DIM / 32), dim3(256), 0, stream>>>(
      Wo, Wot, INNER, DIM);

  // Q projection (head-blocked bf16, pre-scaled 1/8)
  k_gemm<2, false, 2, 9><<<dim3(64), dim3(512), 0, stream>>>(
      x, Wqt, Qh, nullptr, B_SZ * N_Q, INNER, DIM, 0.125f);

  // fused K+V projection: m97 geometry, 2048 blocks
  k_gemm_kv<<<dim3(2048), dim3(256), 0, stream>>>(ctx, Wkvt, Kh, Vt);

  k_attn<<<dim3(B_SZ * NHEADS * (N_Q / 64)), dim3(256), 0, stream>>>(Qh, Kh, Vt, Aat);

  // output projection (bf16 A) + bias, fp32 out
  k_gemm<0, true, 4, 0><<<dim3(128), dim3(512), 0, stream>>>(
      Aat, Wot, out, bo, B_SZ * N_Q, DIM, INNER, 1.0f);
}